// Round 2
// baseline (139.443 us; speedup 1.0000x reference)
//
#include <hip/hip_runtime.h>
#include <math.h>

#define NPIX 262144   // 512*512
#define NKER 15
#define PI_F 3.14159265358979323846f
#define HW 264        // half-plane row stride (float2): 257 used, padded to 8
#define CS 578        // wave scratch stride (float2): >= SK(511)=574
#define SK(n) ((n) + ((n) >> 3))   // skewed LDS index: <=4-way conflicts

typedef float f2 __attribute__((ext_vector_type(2)));

__device__ __forceinline__ f2 mkf2(float a, float b) { f2 r; r.x = a; r.y = b; return r; }
// complex helpers on packed f32 pairs — shaped for v_pk_add/mul/fma_f32
__device__ __forceinline__ f2 rotp(f2 a) { return mkf2(-a.y, a.x); }   // * +i
__device__ __forceinline__ f2 rotm(f2 a) { return mkf2(a.y, -a.x); }   // * -i
__device__ __forceinline__ f2 cmul(f2 a, f2 b) {
  f2 t = mkf2(a.x, a.x) * b;
  f2 u = mkf2(-a.y, a.y) * mkf2(b.y, b.x);
  return t + u;
}
__device__ __forceinline__ f2 cmulc(f2 a, f2 b) {   // a * conj(b)
  f2 t = a * mkf2(b.x, b.x);
  f2 u = mkf2(a.y, -a.x) * mkf2(b.y, b.y);
  return t + u;
}
__device__ __forceinline__ f2 vmin(f2 a, f2 b) { return __builtin_elementwise_min(a, b); }
__device__ __forceinline__ f2 vmax(f2 a, f2 b) { return __builtin_elementwise_max(a, b); }
__device__ __forceinline__ f2 vabs(f2 a) { return __builtin_elementwise_abs(a); }

// Per-thread twiddle power tables: pA[q-1] = w1^q, pB[q-1] = wh^q (q=1..7).
__device__ __forceinline__ void build_tw(int lane, f2* pA, f2* pB) {
  float s, c;
  sincosf(-2.0f * PI_F * (float)lane / 512.0f, &s, &c);
  f2 w1 = mkf2(c, s);
  int h = lane & ~7;
  f2 wh = mkf2(__shfl(c, h, 64), __shfl(s, h, 64));
  pA[0] = w1;
  pA[1] = cmul(w1, w1);
  pA[2] = cmul(pA[1], w1);
  pA[3] = cmul(pA[1], pA[1]);
  pA[4] = cmul(pA[3], w1);
  pA[5] = cmul(pA[3], pA[1]);
  pA[6] = cmul(pA[3], pA[2]);
  pB[0] = wh;
  pB[1] = cmul(wh, wh);
  pB[2] = cmul(pB[1], wh);
  pB[3] = cmul(pB[1], pB[1]);
  pB[4] = cmul(pB[3], wh);
  pB[5] = cmul(pB[3], pB[1]);
  pB[6] = cmul(pB[3], pB[2]);
}

template <bool INV>
__device__ __forceinline__ void dft8(f2 a[8]) {
  const float R = 0.70710678118654752f;
  f2 t0 = a[0] + a[4], u0 = a[0] - a[4];
  f2 t1 = a[1] + a[5], u1 = a[1] - a[5];
  f2 t2 = a[2] + a[6], u2 = a[2] - a[6];
  f2 t3 = a[3] + a[7], u3 = a[3] - a[7];
  u1 = (INV ? (u1 + rotp(u1)) : (u1 + rotm(u1))) * R;
  u2 = INV ? rotp(u2) : rotm(u2);
  u3 = (INV ? (rotp(u3) - u3) : (rotm(u3) - u3)) * R;
  f2 e0 = t0 + t2, f0 = t0 - t2;
  f2 e1 = t1 + t3, f1 = t1 - t3;
  f1 = INV ? rotp(f1) : rotm(f1);
  f2 g0 = u0 + u2, h0 = u0 - u2;
  f2 g1 = u1 + u3, h1 = u1 - u3;
  h1 = INV ? rotp(h1) : rotm(h1);
  a[0] = e0 + e1; a[4] = e0 - e1;
  a[2] = f0 + f1; a[6] = f0 - f1;
  a[1] = g0 + g1; a[5] = g0 - g1;
  a[3] = h0 + h1; a[7] = h0 - h1;
}

// 512-pt Stockham radix-8, one wave, 8 pts/thread, a[q] = point (lane+64q).
template <bool INV>
__device__ __forceinline__ void fft512_r8(f2 a[8], f2* buf, int lane,
                                          const f2* pA, const f2* pB) {
  dft8<INV>(a);
#pragma unroll
  for (int q = 1; q < 8; ++q) a[q] = INV ? cmulc(a[q], pA[q - 1]) : cmul(a[q], pA[q - 1]);
#pragma unroll
  for (int q = 0; q < 8; ++q) buf[9 * lane + q] = a[q];
#pragma unroll
  for (int q = 0; q < 8; ++q) a[q] = buf[SK(lane + 64 * q)];
  dft8<INV>(a);
#pragma unroll
  for (int q = 1; q < 8; ++q) a[q] = INV ? cmulc(a[q], pB[q - 1]) : cmul(a[q], pB[q - 1]);
  int h = lane & ~7;
  int b2 = 9 * h + (lane - h);
#pragma unroll
  for (int q = 0; q < 8; ++q) buf[b2 + 9 * q] = a[q];
#pragma unroll
  for (int q = 0; q < 8; ++q) a[q] = buf[SK(lane + 64 * q)];
  dft8<INV>(a);
}

// After packed FFT Z of (seqA + i seqB): write half-plane spectra of both.
__device__ __forceinline__ void split_store_halfplane(f2 a[8], f2* buf, int lane,
                                                      f2* d0, f2* d1) {
#pragma unroll
  for (int q = 0; q < 8; ++q) buf[SK(lane + 64 * q)] = a[q];
#pragma unroll
  for (int q = 0; q < 4; ++q) {
    int v = lane + 64 * q;
    int mir = (512 - v) & 511;
    f2 P = a[q];
    f2 Qc = buf[SK(mir)];
    d0[v] = (P + mkf2(Qc.x, -Qc.y)) * 0.5f;
    d1[v] = mkf2(0.5f * (P.y + Qc.y), 0.5f * (Qc.x - P.x));
  }
  if (lane == 0) {
    f2 P = a[4];
    d0[256] = mkf2(P.x, 0.f);
    d1[256] = mkf2(P.y, 0.f);
  }
}

// ---- rows_all (512 threads, 8 waves) ----
// blocks 0..511: kernel row FFTs (+ zero-row skip), row sums.
// blocks 512..607: R2C row FFTs of x.
__global__ __launch_bounds__(512, 4) void rows_all(
    const float* __restrict__ Ks, const float* __restrict__ x,
    float* __restrict__ partial, f2* __restrict__ AkH,
    f2* __restrict__ AxH) {
  __shared__ float krow[512 * NKER];   // 30720 B
  __shared__ f2 scr[8][CS];            // 36992 B
  __shared__ float psum[480];          // 1920 B
  int t = threadIdx.x, wave = t >> 6, lane = t & 63;
  f2 pA[7], pB[7];
  build_tw(lane, pA, pB);
  if (blockIdx.x < 512) {
    int b = blockIdx.x;              // output row
    int rs = (b + 256) & 511;        // fftshift row source
    const f2* src = (const f2*)Ks + (size_t)rs * 3840;
    f2* kr2 = (f2*)krow;
    for (int i = t; i < 3840; i += 512) kr2[i] = src[i];
    __syncthreads();
    // row sums: 15 k x 32 y-groups of 16
    if (t < 480) {
      int k = t >> 5, yg = t & 31;
      float s = 0.f;
      int base = yg * 16;
#pragma unroll
      for (int y = 0; y < 16; ++y) s += krow[(base + y) * NKER + k];
      psum[t] = s;
    }
    // one packed k-pair FFT per wave
    {
      int k1 = 2 * wave, k2 = k1 + 1;     // k2==15 -> dummy plane
      f2 a[8];
      bool nz = false;
#pragma unroll
      for (int q = 0; q < 8; ++q) {
        int ys = (lane + 64 * q + 256) & 511;   // fftshift col
        float re = krow[ys * NKER + k1];
        float im = (k2 < NKER) ? krow[ys * NKER + k2] : 0.f;
        a[q] = mkf2(re, im);
        nz |= (re != 0.f) || (im != 0.f);
      }
      f2* d0 = AkH + ((size_t)k1 * 512 + b) * HW;
      f2* d1 = AkH + ((size_t)k2 * 512 + b) * HW;   // plane 15 = scratch
      if (__any((int)nz)) {
        fft512_r8<false>(a, &scr[wave][0], lane, pA, pB);
        split_store_halfplane(a, &scr[wave][0], lane, d0, d1);
      } else {
        // exactly-zero kernel row -> exactly-zero spectrum
        f2 z = mkf2(0.f, 0.f);
#pragma unroll
        for (int q = 0; q < 4; ++q) { int v = lane + 64 * q; d0[v] = z; d1[v] = z; }
        if (lane == 0) { d0[256] = z; d1[256] = z; }
      }
    }
    __syncthreads();
    if (t < NKER) {
      float s = 0.f;
#pragma unroll
      for (int g = 0; g < 32; ++g) s += psum[(t << 5) + g];
      partial[b * 16 + t] = s;
    }
  } else {
    int job = (blockIdx.x - 512) * 8 + wave;   // 0..767
    int c = job >> 8;                // channel 0..2
    int rp = job & 255;              // row-pair 0..255
    int r0 = rp, r1 = rp + 256;
    f2 a[8];
#pragma unroll
    for (int q = 0; q < 8; ++q) {
      int y = lane + 64 * q;
      a[q] = mkf2(x[((size_t)r0 * 512 + y) * 3 + c],
                  x[((size_t)r1 * 512 + y) * 3 + c]);
    }
    fft512_r8<false>(a, &scr[wave][0], lane, pA, pB);
    f2* d0 = AxH + ((size_t)c * 512 + r0) * HW;
    f2* d1 = AxH + ((size_t)c * 512 + r1) * HW;
    split_store_halfplane(a, &scr[wave][0], lane, d0, d1);
  }
}

// ---- x column FFT hoist: 4-col slabs, 256 threads (4 waves).
//      grid (67, 3): bx==66,by==0 does the ksum reduction. ----
__global__ __launch_bounds__(256, 4) void xcols(const f2* __restrict__ AxH,
                                                f2* __restrict__ FxT,
                                                const float* __restrict__ partial,
                                                float* __restrict__ sums) {
  __shared__ f2 buf[4 * CS];   // 18496 B
  __shared__ float red[256];
  int t = threadIdx.x;
  if (blockIdx.x == 66) {
    if (blockIdx.y != 0) return;
    int k = t & 15, g = t >> 4;        // 16 groups x 16 slots
    float acc = 0.f;
    for (int b = g; b < 512; b += 16) acc += partial[b * 16 + k];
    red[t] = acc;
    __syncthreads();
    if (t < 16) {
      float s = 0.f;
#pragma unroll
      for (int g2 = 0; g2 < 16; ++g2) s += red[g2 * 16 + t];
      sums[t] = s;
    }
    return;
  }
  int c = t >> 6, lane = t & 63;
  int col0 = blockIdx.x << 2, ch = blockIdx.y;
  f2 pA[7], pB[7];
  build_tw(lane, pA, pB);
  const f2* bx = AxH + (size_t)ch * 512 * HW;
#pragma unroll
  for (int u = 0; u < 8; ++u) {
    int idx = (u << 8) + t;
    int row = idx >> 2, cc = idx & 3;
    buf[cc * CS + SK(row)] = bx[(size_t)row * HW + col0 + cc];
  }
  __syncthreads();
  f2 a[8];
#pragma unroll
  for (int q = 0; q < 8; ++q) a[q] = buf[c * CS + SK(lane + 64 * q)];
  fft512_r8<false>(a, &buf[c * CS], lane, pA, pB);
  f2* dst = FxT + ((size_t)ch * HW + col0 + c) * 512;
#pragma unroll
  for (int q = 0; q < 8; ++q) dst[lane + 64 * q] = a[q];
}

// ---- fused column pass: 4-col slabs, 256 threads, grid (66, 15).
//      stage Ak slab -> fwd FFT -> * Fx -> inv FFT -> store. ----
__global__ __launch_bounds__(256, 4) void fused_cols(
    f2* __restrict__ AkH, const f2* __restrict__ FxT,
    const int* __restrict__ c0) {
  __shared__ f2 buf[4 * CS];   // 18496 B
  int t = threadIdx.x;
  int col0 = blockIdx.x << 2, k = blockIdx.y;
  int c = t >> 6, lane = t & 63;
  f2 pA[7], pB[7];
  build_tw(lane, pA, pB);
  f2* bk = AkH + (size_t)k * 512 * HW;
  // stage Ak slab
#pragma unroll
  for (int u = 0; u < 8; ++u) {
    int idx = (u << 8) + t;
    int row = idx >> 2, cc = idx & 3;
    buf[cc * CS + SK(row)] = bk[(size_t)row * HW + col0 + cc];
  }
  // issue Fx loads early: latency hides under the barrier + fwd FFT
  const f2* fx = FxT + ((size_t)c0[k] * HW + col0 + c) * 512;
  f2 xq[8];
#pragma unroll
  for (int q = 0; q < 8; ++q) xq[q] = fx[lane + 64 * q];
  __syncthreads();
  f2 a[8];
#pragma unroll
  for (int q = 0; q < 8; ++q) a[q] = buf[c * CS + SK(lane + 64 * q)];
  fft512_r8<false>(a, &buf[c * CS], lane, pA, pB);
#pragma unroll
  for (int q = 0; q < 8; ++q) a[q] = cmul(a[q], xq[q]);
  fft512_r8<true>(a, &buf[c * CS], lane, pA, pB);
#pragma unroll
  for (int q = 0; q < 8; ++q) buf[c * CS + SK(lane + 64 * q)] = a[q];
  __syncthreads();
#pragma unroll
  for (int u = 0; u < 8; ++u) {
    int idx = (u << 8) + t;
    int row = idx >> 2, cc = idx & 3;
    bk[(size_t)row * HW + col0 + cc] = buf[cc * CS + SK(row)];
  }
}

// ---- C2R inverse row FFT + deferred norm + growth + combine -> Hs ----
__global__ __launch_bounds__(512, 4) void irows_growth_combine(
    const f2* __restrict__ AkH, const float* __restrict__ sums,
    const float* __restrict__ m, const float* __restrict__ s,
    const float* __restrict__ h, const float* __restrict__ w,
    float* __restrict__ Hs) {
  __shared__ f2 scr[8][CS];            // 36992 B
  __shared__ float accL[4][3][512];    // 24576 B
  __shared__ float mk[16], isk[16], hk[16], wk[16][3], sck[16];
  int t = threadIdx.x, wave = t >> 6, lane = t & 63;
  int row = blockIdx.x;
  if (t < NKER) {
    mk[t] = m[t]; isk[t] = 1.0f / s[t]; hk[t] = h[t];
    sck[t] = 1.0f / (sums[t] * 262144.0f);
    wk[t][0] = w[t * 3 + 0]; wk[t][1] = w[t * 3 + 1]; wk[t][2] = w[t * 3 + 2];
  }
  __syncthreads();
  f2 pA[7], pB[7];
  build_tw(lane, pA, pB);
  float acc[3][8];
#pragma unroll
  for (int cc = 0; cc < 3; ++cc)
#pragma unroll
    for (int q = 0; q < 8; ++q) acc[cc][q] = 0.f;
  {
    int slot = wave;
    int k1 = 2 * slot, k2 = 2 * slot + 1;
    bool dual = (k2 < NKER);
    const f2* p1 = AkH + ((size_t)k1 * 512 + row) * HW;
    const f2* p2 = AkH + ((size_t)(dual ? k2 : k1) * 512 + row) * HW;
    f2 a[8];
#pragma unroll
    for (int q = 0; q < 8; ++q) {
      int v = lane + 64 * q;
      if (v <= 256) {
        f2 A1 = p1[v];
        f2 A2 = dual ? p2[v] : mkf2(0.f, 0.f);
        a[q] = mkf2(A1.x - A2.y, A1.y + A2.x);          // A1 + i*A2
      } else {
        int mi = 512 - v;
        f2 A1 = p1[mi];
        f2 A2 = dual ? p2[mi] : mkf2(0.f, 0.f);
        a[q] = mkf2(A1.x + A2.y, -A1.y + A2.x);         // conj(A1) + i*conj(A2)
      }
    }
    fft512_r8<true>(a, &scr[wave][0], lane, pA, pB);
    float m1 = mk[k1], i1 = isk[k1], h1 = hk[k1], s1 = sck[k1];
    float w10 = wk[k1][0], w11 = wk[k1][1], w12 = wk[k1][2];
#pragma unroll
    for (int q = 0; q < 8; ++q) {
      float tt = (a[q].x * s1 - m1) * i1;
      float g = (expf(-0.5f * tt * tt) * 2.0f - 1.0f) * h1;
      acc[0][q] += g * w10; acc[1][q] += g * w11; acc[2][q] += g * w12;
    }
    if (dual) {
      float m2 = mk[k2], i2 = isk[k2], h2 = hk[k2], s2 = sck[k2];
      float w20 = wk[k2][0], w21 = wk[k2][1], w22 = wk[k2][2];
#pragma unroll
      for (int q = 0; q < 8; ++q) {
        float tt = (a[q].y * s2 - m2) * i2;
        float g = (expf(-0.5f * tt * tt) * 2.0f - 1.0f) * h2;
        acc[0][q] += g * w20; acc[1][q] += g * w21; acc[2][q] += g * w22;
      }
    }
  }
  if (wave < 4) {
#pragma unroll
    for (int cc = 0; cc < 3; ++cc)
#pragma unroll
      for (int q = 0; q < 8; ++q) accL[wave][cc][lane + 64 * q] = acc[cc][q];
  }
  __syncthreads();
  if (wave >= 4) {
#pragma unroll
    for (int cc = 0; cc < 3; ++cc)
#pragma unroll
      for (int q = 0; q < 8; ++q) accL[wave - 4][cc][lane + 64 * q] += acc[cc][q];
  }
  __syncthreads();
#pragma unroll
  for (int cc = 0; cc < 3; ++cc) {
    float v = accL[0][cc][t] + accL[1][cc][t] + accL[2][cc][t] + accL[3][cc][t];
    Hs[(size_t)cc * NPIX + (size_t)row * 512 + t] = v;
  }
}

// ---- fused flow + reintegrate: 16x16 output tile, packed (y,x) math ----
__global__ void flow_reint(const float* __restrict__ x, const float* __restrict__ Hs,
                           float* __restrict__ out) {
  __shared__ float tS[7][496];     // 22*22=484 used, planar
  __shared__ f2 muF[400 * 3];      // (mu_x, mu_y) per halo cell per channel
  int ox = (blockIdx.x >> 5) << 4;
  int oy = (blockIdx.x & 31) << 4;
  // pass 0: stage 22x22 tile
  for (int i = threadIdx.x; i < 484; i += 256) {
    int li = i / 22, lj = i % 22;
    int qx = (ox - 3 + li) & 511, qy = (oy - 3 + lj) & 511;
    int q = (qx << 9) | qy;
    float h0 = Hs[q], h1 = Hs[NPIX + q], h2 = Hs[2 * NPIX + q];
    float x0 = x[(size_t)q * 3 + 0], x1 = x[(size_t)q * 3 + 1], x2 = x[(size_t)q * 3 + 2];
    tS[0][i] = h0; tS[1][i] = h1; tS[2][i] = h2;
    tS[3][i] = x0 + x1 + x2;
    tS[4][i] = x0; tS[5][i] = x1; tS[6][i] = x2;
  }
  __syncthreads();
  // pass 1: sobel + flow + mu over the 20x20 halo, packed (wy,wx)
  for (int i = threadIdx.x; i < 400; i += 256) {
    int hi = i / 20, hj = i % 20;
    int qx = (ox - 2 + hi) & 511, qy = (oy - 2 + hj) & 511;
    f2 sH0 = mkf2(0.f, 0.f), sH1 = sH0, sH2 = sH0, sX = sH0;   // (sy, sx)
#pragma unroll
    for (int di = -1; di <= 1; ++di) {
#pragma unroll
      for (int dj = -1; dj <= 1; ++dj) {
        if (di == 0 && dj == 0) continue;
        int xi = qx + di, yj = qy + dj;
        if ((unsigned)xi >= 512u || (unsigned)yj >= 512u) continue;  // zero pad
        int l = (hi + 1 + di) * 22 + (hj + 1 + dj);
        float wy = (float)di * ((dj == 0) ? 2.f : 1.f);
        float wx = (float)dj * ((di == 0) ? 2.f : 1.f);
        f2 wv = mkf2(wy, wx);
        sH0 += wv * tS[0][l];
        sH1 += wv * tS[1][l];
        sH2 += wv * tS[2][l];
        sX  += wv * tS[3][l];
      }
    }
    int lc = (hi + 1) * 22 + (hj + 1);
    f2 ctr = mkf2((float)qx + 0.5f, (float)qy + 0.5f);
    f2 sH[3] = {sH0, sH1, sH2};
    const f2 lo = mkf2(-1.05f, -1.05f), hi2 = mkf2(1.05f, 1.05f);
    const f2 mlo = mkf2(0.95f, 0.95f), mhi = mkf2(511.05f, 511.05f);
#pragma unroll
    for (int c = 0; c < 3; ++c) {
      float xc = tS[4 + c][lc];
      float tt = xc * 0.5f;
      float alpha = fminf(tt * tt, 1.0f);
      f2 F = sH[c] * (1.f - alpha) - sX * alpha;
      f2 mu = ctr + vmin(vmax(F * 0.2f, lo), hi2);
      muF[i * 3 + c] = vmin(vmax(mu, mlo), mhi);
    }
  }
  __syncthreads();
  // pass 2: 5x5 reintegration gather, packed clamps
  int o = threadIdx.x;
  int lx = o >> 4, ly = o & 15;
  int px_ = ox + lx, py_ = oy + ly;
  f2 ctr = mkf2((float)px_ + 0.5f, (float)py_ + 0.5f);
  const f2 c145 = mkf2(1.45f, 1.45f), c0f = mkf2(0.f, 0.f), c1f = mkf2(1.f, 1.f);
  float a0 = 0.f, a1 = 0.f, a2 = 0.f;
#pragma unroll
  for (int dx = -2; dx <= 2; ++dx) {
    int hi = lx + 2 - dx;
#pragma unroll
    for (int dy = -2; dy <= 2; ++dy) {
      int hj = ly + 2 - dy;
      int cell = hi * 20 + hj;
      int lb = (hi + 1) * 22 + (hj + 1);
      f2 w0 = vmin(vmax(c145 - vabs(ctr - muF[cell * 3 + 0]), c0f), c1f);
      a0 += tS[4][lb] * (w0.x * w0.y);
      f2 w1 = vmin(vmax(c145 - vabs(ctr - muF[cell * 3 + 1]), c0f), c1f);
      a1 += tS[5][lb] * (w1.x * w1.y);
      f2 w2 = vmin(vmax(c145 - vabs(ctr - muF[cell * 3 + 2]), c0f), c1f);
      a2 += tS[6][lb] * (w2.x * w2.y);
    }
  }
  const float inv_area = 0.27700831f;  // 1/(4*0.95^2)
  size_t p = (size_t)((px_ << 9) | py_);
  out[p * 3 + 0] = a0 * inv_area;
  out[p * 3 + 1] = a1 * inv_area;
  out[p * 3 + 2] = a2 * inv_area;
}

extern "C" void kernel_launch(void* const* d_in, const int* in_sizes, int n_in,
                              void* d_out, int out_size, void* d_ws, size_t ws_size,
                              hipStream_t stream) {
  const float* x    = (const float*)d_in[0];
  const float* Ks   = (const float*)d_in[1];
  const float* m    = (const float*)d_in[2];
  const float* s    = (const float*)d_in[3];
  const float* h    = (const float*)d_in[4];
  const float* w_c1 = (const float*)d_in[5];
  const int*   c0   = (const int*)d_in[6];
  float* out = (float*)d_out;

  char* ws = (char*)d_ws;
  size_t off = 0;
  float* sums    = (float*)(ws + off); off += 1024;
  float* partial = (float*)(ws + off); off += 512 * 16 * 4;
  f2* AxH  = (f2*)(ws + off); off += (size_t)3 * 512 * HW * 8;    // 3.2 MB
  f2* AkH  = (f2*)(ws + off); off += (size_t)16 * 512 * HW * 8;   // 17.3 MB (plane 15 dummy)
  f2* FxT  = (f2*)(ws + off); off += (size_t)3 * HW * 512 * 8;    // 3.2 MB (transposed Fx)
  float* Hs = (float*)(ws + off); off += (size_t)3 * NPIX * 4;    // 3 MB

  rows_all<<<608, 512, 0, stream>>>(Ks, x, partial, AkH, AxH);
  xcols<<<dim3(67, 3), 256, 0, stream>>>(AxH, FxT, partial, sums);
  fused_cols<<<dim3(66, NKER), 256, 0, stream>>>(AkH, FxT, c0);
  irows_growth_combine<<<512, 512, 0, stream>>>(AkH, sums, m, s, h, w_c1, Hs);
  flow_reint<<<1024, 256, 0, stream>>>(x, Hs, out);
}

// Round 3
// 127.451 us; speedup vs baseline: 1.0941x; 1.0941x over previous
//
#include <hip/hip_runtime.h>
#include <math.h>

#define NPIX 262144   // 512*512
#define NKER 15
#define PI_F 3.14159265358979323846f
#define HW 264        // half-plane row stride (float2): 257 used, padded to 8
#define CS 578        // wave scratch stride (float2): >= SK(511)=574
#define SK(n) ((n) + ((n) >> 3))   // skewed LDS index: <=4-way conflicts

__device__ __forceinline__ float2 cadd(float2 a, float2 b) { return make_float2(a.x + b.x, a.y + b.y); }
__device__ __forceinline__ float2 csub(float2 a, float2 b) { return make_float2(a.x - b.x, a.y - b.y); }
__device__ __forceinline__ float2 cmul(float2 a, float2 b) {
  return make_float2(a.x * b.x - a.y * b.y, a.x * b.y + a.y * b.x);
}
__device__ __forceinline__ float2 cmulc(float2 a, float2 b) {   // a * conj(b)
  return make_float2(a.x * b.x + a.y * b.y, a.y * b.x - a.x * b.y);
}

// Per-thread twiddle power tables: pA[q-1] = w1^q, pB[q-1] = wh^q (q=1..7).
// Built once per kernel; log-depth powering (no 7-deep serial chain).
__device__ __forceinline__ void build_tw(int lane, float2* pA, float2* pB) {
  float s, c;
  sincosf(-2.0f * PI_F * (float)lane / 512.0f, &s, &c);
  float2 w1 = make_float2(c, s);
  int h = lane & ~7;
  float2 wh = make_float2(__shfl(c, h, 64), __shfl(s, h, 64));
  pA[0] = w1;
  pA[1] = cmul(w1, w1);
  pA[2] = cmul(pA[1], w1);
  pA[3] = cmul(pA[1], pA[1]);
  pA[4] = cmul(pA[3], w1);
  pA[5] = cmul(pA[3], pA[1]);
  pA[6] = cmul(pA[3], pA[2]);
  pB[0] = wh;
  pB[1] = cmul(wh, wh);
  pB[2] = cmul(pB[1], wh);
  pB[3] = cmul(pB[1], pB[1]);
  pB[4] = cmul(pB[3], wh);
  pB[5] = cmul(pB[3], pB[1]);
  pB[6] = cmul(pB[3], pB[2]);
}

template <bool INV>
__device__ __forceinline__ void dft8(float2 a[8]) {
  const float R = 0.70710678118654752f;
  float2 t0 = cadd(a[0], a[4]), u0 = csub(a[0], a[4]);
  float2 t1 = cadd(a[1], a[5]), u1 = csub(a[1], a[5]);
  float2 t2 = cadd(a[2], a[6]), u2 = csub(a[2], a[6]);
  float2 t3 = cadd(a[3], a[7]), u3 = csub(a[3], a[7]);
  u1 = INV ? make_float2(R * (u1.x - u1.y), R * (u1.x + u1.y))
           : make_float2(R * (u1.x + u1.y), R * (u1.y - u1.x));
  u2 = INV ? make_float2(-u2.y, u2.x) : make_float2(u2.y, -u2.x);
  u3 = INV ? make_float2(-R * (u3.x + u3.y), R * (u3.x - u3.y))
           : make_float2(R * (u3.y - u3.x), -R * (u3.x + u3.y));
  float2 e0 = cadd(t0, t2), f0 = csub(t0, t2);
  float2 e1 = cadd(t1, t3), f1 = csub(t1, t3);
  f1 = INV ? make_float2(-f1.y, f1.x) : make_float2(f1.y, -f1.x);
  float2 g0 = cadd(u0, u2), h0 = csub(u0, u2);
  float2 g1 = cadd(u1, u3), h1 = csub(u1, u3);
  h1 = INV ? make_float2(-h1.y, h1.x) : make_float2(h1.y, -h1.x);
  a[0] = cadd(e0, e1); a[4] = csub(e0, e1);
  a[2] = cadd(f0, f1); a[6] = csub(f0, f1);
  a[1] = cadd(g0, g1); a[5] = csub(g0, g1);
  a[3] = cadd(h0, h1); a[7] = csub(h0, h1);
}

// 512-pt Stockham radix-8, one wave, 8 pts/thread, a[q] = point (lane+64q).
// Twiddles come from the precomputed tables; INV applies conj via cmulc.
template <bool INV>
__device__ __forceinline__ void fft512_r8(float2 a[8], float2* buf, int lane,
                                          const float2* pA, const float2* pB) {
  dft8<INV>(a);
#pragma unroll
  for (int q = 1; q < 8; ++q) a[q] = INV ? cmulc(a[q], pA[q - 1]) : cmul(a[q], pA[q - 1]);
#pragma unroll
  for (int q = 0; q < 8; ++q) buf[9 * lane + q] = a[q];
#pragma unroll
  for (int q = 0; q < 8; ++q) a[q] = buf[SK(lane + 64 * q)];
  dft8<INV>(a);
#pragma unroll
  for (int q = 1; q < 8; ++q) a[q] = INV ? cmulc(a[q], pB[q - 1]) : cmul(a[q], pB[q - 1]);
  int h = lane & ~7;
  int b2 = 9 * h + (lane - h);
#pragma unroll
  for (int q = 0; q < 8; ++q) buf[b2 + 9 * q] = a[q];
#pragma unroll
  for (int q = 0; q < 8; ++q) a[q] = buf[SK(lane + 64 * q)];
  dft8<INV>(a);
}

// After packed FFT Z of (seqA + i seqB): write half-plane spectra of both.
__device__ __forceinline__ void split_store_halfplane(float2 a[8], float2* buf, int lane,
                                                      float2* d0, float2* d1) {
#pragma unroll
  for (int q = 0; q < 8; ++q) buf[SK(lane + 64 * q)] = a[q];
#pragma unroll
  for (int q = 0; q < 4; ++q) {
    int v = lane + 64 * q;
    int mir = (512 - v) & 511;
    float2 P = a[q];
    float2 Qc = buf[SK(mir)];
    float2 Q = make_float2(Qc.x, -Qc.y);
    d0[v] = make_float2(0.5f * (P.x + Q.x), 0.5f * (P.y + Q.y));
    d1[v] = make_float2(0.5f * (P.y - Q.y), -0.5f * (P.x - Q.x));
  }
  if (lane == 0) {
    float2 P = a[4];
    d0[256] = make_float2(P.x, 0.f);
    d1[256] = make_float2(P.y, 0.f);
  }
}

// ---- rows_all (512 threads, 8 waves) ----
// blocks 0..511: output row b of shifted kernels — stage Ks source row
//   (b+256)&511 into LDS; row-sums -> partial; 8 waves each do ONE packed
//   k-pair FFT (slot=wave; plane 15 = dummy) -> AkH (UNSCALED).
//   Exact-zero rows (ring kernels have compact support; expf underflow
//   gives true zeros beyond the ring) skip the FFT and store zeros —
//   bit-exact, wave-uniform branch.
// blocks 512..607: R2C row FFTs of x, 8 wave-jobs per block (3ch x 256 pairs).
__global__ __launch_bounds__(512, 4) void rows_all(
    const float* __restrict__ Ks, const float* __restrict__ x,
    float* __restrict__ partial, float2* __restrict__ AkH,
    float2* __restrict__ AxH) {
  __shared__ float krow[512 * NKER];   // 30720 B
  __shared__ float2 scr[8][CS];        // 36992 B
  __shared__ float psum[480];          // 1920 B
  int t = threadIdx.x, wave = t >> 6, lane = t & 63;
  float2 pA[7], pB[7];
  build_tw(lane, pA, pB);
  if (blockIdx.x < 512) {
    int b = blockIdx.x;              // output row
    int rs = (b + 256) & 511;        // fftshift row source
    const float2* src = (const float2*)Ks + (size_t)rs * 3840;
    float2* kr2 = (float2*)krow;
    for (int i = t; i < 3840; i += 512) kr2[i] = src[i];
    __syncthreads();
    // row sums: 15 k x 32 y-groups of 16  (512 threads cover all 480 slots)
    if (t < 480) {
      int k = t >> 5, yg = t & 31;
      float s = 0.f;
      int base = yg * 16;
#pragma unroll
      for (int y = 0; y < 16; ++y) s += krow[(base + y) * NKER + k];
      psum[t] = s;
    }
    // one packed k-pair FFT per wave: slot = wave (0..7)
    {
      int k1 = 2 * wave, k2 = k1 + 1;     // k2==15 -> dummy plane
      float2 a[8];
      bool nz = false;
#pragma unroll
      for (int q = 0; q < 8; ++q) {
        int ys = (lane + 64 * q + 256) & 511;   // fftshift col
        float re = krow[ys * NKER + k1];
        float im = (k2 < NKER) ? krow[ys * NKER + k2] : 0.f;
        a[q] = make_float2(re, im);
        nz |= (re != 0.f) || (im != 0.f);
      }
      float2* d0 = AkH + ((size_t)k1 * 512 + b) * HW;
      float2* d1 = AkH + ((size_t)k2 * 512 + b) * HW;   // plane 15 = scratch
      if (__any((int)nz)) {
        fft512_r8<false>(a, &scr[wave][0], lane, pA, pB);
        split_store_halfplane(a, &scr[wave][0], lane, d0, d1);
      } else {
        // exactly-zero kernel row -> exactly-zero spectrum (bit-exact skip)
        float2 z = make_float2(0.f, 0.f);
#pragma unroll
        for (int q = 0; q < 4; ++q) { int v = lane + 64 * q; d0[v] = z; d1[v] = z; }
        if (lane == 0) { d0[256] = z; d1[256] = z; }
      }
    }
    __syncthreads();
    if (t < NKER) {
      float s = 0.f;
#pragma unroll
      for (int g = 0; g < 32; ++g) s += psum[(t << 5) + g];
      partial[b * 16 + t] = s;
    }
  } else {
    int job = (blockIdx.x - 512) * 8 + wave;   // 0..767
    int c = job >> 8;                // channel 0..2
    int rp = job & 255;              // row-pair 0..255
    int r0 = rp, r1 = rp + 256;
    float2 a[8];
#pragma unroll
    for (int q = 0; q < 8; ++q) {
      int y = lane + 64 * q;
      a[q] = make_float2(x[((size_t)r0 * 512 + y) * 3 + c],
                         x[((size_t)r1 * 512 + y) * 3 + c]);
    }
    fft512_r8<false>(a, &scr[wave][0], lane, pA, pB);
    float2* d0 = AxH + ((size_t)c * 512 + r0) * HW;
    float2* d1 = AxH + ((size_t)c * 512 + r1) * HW;
    split_store_halfplane(a, &scr[wave][0], lane, d0, d1);
  }
}

// ---- x column FFT hoist: compute Fx = colFFT(AxH) ONCE per channel,
//      store TRANSPOSED (FxT[ch][col][row]) so fused_cols can read its
//      xh fragments with direct coalesced global loads (512B/instr). ----
__global__ __launch_bounds__(512, 4) void xcols(const float2* __restrict__ AxH,
                                                float2* __restrict__ FxT) {
  __shared__ float2 buf[8 * CS];   // 36992 B
  int t = threadIdx.x, c = t >> 6, lane = t & 63;
  int col0 = blockIdx.x << 3, ch = blockIdx.y;
  float2 pA[7], pB[7];
  build_tw(lane, pA, pB);
  const float2* bx = AxH + (size_t)ch * 512 * HW;
#pragma unroll
  for (int u = 0; u < 8; ++u) {
    int idx = (u << 9) + t;
    int row = idx >> 3, cc = idx & 7;
    buf[cc * CS + SK(row)] = bx[(size_t)row * HW + col0 + cc];
  }
  __syncthreads();
  float2 a[8];
#pragma unroll
  for (int q = 0; q < 8; ++q) a[q] = buf[c * CS + SK(lane + 64 * q)];
  fft512_r8<false>(a, &buf[c * CS], lane, pA, pB);
  float2* dst = FxT + ((size_t)ch * HW + col0 + c) * 512;
#pragma unroll
  for (int q = 0; q < 8; ++q) dst[lane + 64 * q] = a[q];
}

// ---- fused column pass (512 threads): stage Ak slab -> fwd FFT ->
//      * precomputed Fx (direct coalesced reads) -> inv FFT -> store.
//      block (33, 0) = ksum_final; blocks (33, y>0) exit immediately. ----
__global__ __launch_bounds__(512, 4) void fused_cols(
    float2* __restrict__ AkH, const float2* __restrict__ FxT,
    const int* __restrict__ c0, const float* __restrict__ partial,
    float* __restrict__ sums) {
  __shared__ float2 buf[8 * CS];   // 36992 B
  __shared__ float red[512];
  int t = threadIdx.x;
  if (blockIdx.x == 33) {
    if (blockIdx.y != 0) return;
    int k = t & 15, g = t >> 4;        // 32 groups x 16 slots
    float acc = 0.f;
    for (int b = g; b < 512; b += 32) acc += partial[b * 16 + k];
    red[t] = acc;
    __syncthreads();
    if (t < 16) {
      float s = 0.f;
#pragma unroll
      for (int g2 = 0; g2 < 32; ++g2) s += red[g2 * 16 + t];
      sums[t] = s;
    }
    return;
  }
  int col0 = blockIdx.x << 3, k = blockIdx.y;
  int c = t >> 6, lane = t & 63;
  float2 pA[7], pB[7];
  build_tw(lane, pA, pB);
  float2* bk = AkH + (size_t)k * 512 * HW;
  // stage Ak slab (coalesced)
#pragma unroll
  for (int u = 0; u < 8; ++u) {
    int idx = (u << 9) + t;
    int row = idx >> 3, cc = idx & 7;
    buf[cc * CS + SK(row)] = bk[(size_t)row * HW + col0 + cc];
  }
  // issue Fx loads early: independent of LDS, latency hides under fwd FFT
  const float2* fx = FxT + ((size_t)c0[k] * HW + col0 + c) * 512;
  float2 xq[8];
#pragma unroll
  for (int q = 0; q < 8; ++q) xq[q] = fx[lane + 64 * q];
  __syncthreads();
  float2 a[8];
#pragma unroll
  for (int q = 0; q < 8; ++q) a[q] = buf[c * CS + SK(lane + 64 * q)];
  fft512_r8<false>(a, &buf[c * CS], lane, pA, pB);
#pragma unroll
  for (int q = 0; q < 8; ++q) a[q] = cmul(a[q], xq[q]);
  fft512_r8<true>(a, &buf[c * CS], lane, pA, pB);
#pragma unroll
  for (int q = 0; q < 8; ++q) buf[c * CS + SK(lane + 64 * q)] = a[q];
  __syncthreads();
#pragma unroll
  for (int u = 0; u < 8; ++u) {
    int idx = (u << 9) + t;
    int row = idx >> 3, cc = idx & 7;
    bk[(size_t)row * HW + col0 + cc] = buf[cc * CS + SK(row)];
  }
}

// ---- C2R inverse row FFT + deferred norm + growth + combine -> Hs ----
// 512 threads: 8 waves, slot = wave; two-step accL accumulation (4 planes).
__global__ __launch_bounds__(512, 4) void irows_growth_combine(
    const float2* __restrict__ AkH, const float* __restrict__ sums,
    const float* __restrict__ m, const float* __restrict__ s,
    const float* __restrict__ h, const float* __restrict__ w,
    float* __restrict__ Hs) {
  __shared__ float2 scr[8][CS];        // 36992 B
  __shared__ float accL[4][3][512];    // 24576 B
  __shared__ float mk[16], isk[16], hk[16], wk[16][3], sck[16];
  int t = threadIdx.x, wave = t >> 6, lane = t & 63;
  int row = blockIdx.x;
  if (t < NKER) {
    mk[t] = m[t]; isk[t] = 1.0f / s[t]; hk[t] = h[t];
    sck[t] = 1.0f / (sums[t] * 262144.0f);
    wk[t][0] = w[t * 3 + 0]; wk[t][1] = w[t * 3 + 1]; wk[t][2] = w[t * 3 + 2];
  }
  __syncthreads();
  float2 pA[7], pB[7];
  build_tw(lane, pA, pB);
  float acc[3][8];
#pragma unroll
  for (int cc = 0; cc < 3; ++cc)
#pragma unroll
    for (int q = 0; q < 8; ++q) acc[cc][q] = 0.f;
  {
    int slot = wave;
    int k1 = 2 * slot, k2 = 2 * slot + 1;
    bool dual = (k2 < NKER);
    const float2* p1 = AkH + ((size_t)k1 * 512 + row) * HW;
    const float2* p2 = AkH + ((size_t)(dual ? k2 : k1) * 512 + row) * HW;
    float2 a[8];
#pragma unroll
    for (int q = 0; q < 8; ++q) {
      int v = lane + 64 * q;
      if (v <= 256) {
        float2 A1 = p1[v];
        float2 A2 = dual ? p2[v] : make_float2(0.f, 0.f);
        a[q] = make_float2(A1.x - A2.y, A1.y + A2.x);          // A1 + i*A2
      } else {
        int mi = 512 - v;
        float2 A1 = p1[mi];
        float2 A2 = dual ? p2[mi] : make_float2(0.f, 0.f);
        a[q] = make_float2(A1.x + A2.y, -A1.y + A2.x);         // conj(A1) + i*conj(A2)
      }
    }
    fft512_r8<true>(a, &scr[wave][0], lane, pA, pB);
    float m1 = mk[k1], i1 = isk[k1], h1 = hk[k1], s1 = sck[k1];
    float w10 = wk[k1][0], w11 = wk[k1][1], w12 = wk[k1][2];
#pragma unroll
    for (int q = 0; q < 8; ++q) {
      float tt = (a[q].x * s1 - m1) * i1;
      float g = (expf(-0.5f * tt * tt) * 2.0f - 1.0f) * h1;
      acc[0][q] += g * w10; acc[1][q] += g * w11; acc[2][q] += g * w12;
    }
    if (dual) {
      float m2 = mk[k2], i2 = isk[k2], h2 = hk[k2], s2 = sck[k2];
      float w20 = wk[k2][0], w21 = wk[k2][1], w22 = wk[k2][2];
#pragma unroll
      for (int q = 0; q < 8; ++q) {
        float tt = (a[q].y * s2 - m2) * i2;
        float g = (expf(-0.5f * tt * tt) * 2.0f - 1.0f) * h2;
        acc[0][q] += g * w20; acc[1][q] += g * w21; acc[2][q] += g * w22;
      }
    }
  }
  // two-step accumulation into 4 planes (waves 0-3 write, waves 4-7 add)
  if (wave < 4) {
#pragma unroll
    for (int cc = 0; cc < 3; ++cc)
#pragma unroll
      for (int q = 0; q < 8; ++q) accL[wave][cc][lane + 64 * q] = acc[cc][q];
  }
  __syncthreads();
  if (wave >= 4) {
#pragma unroll
    for (int cc = 0; cc < 3; ++cc)
#pragma unroll
      for (int q = 0; q < 8; ++q) accL[wave - 4][cc][lane + 64 * q] += acc[cc][q];
  }
  __syncthreads();
#pragma unroll
  for (int cc = 0; cc < 3; ++cc) {
    float v = accL[0][cc][t] + accL[1][cc][t] + accL[2][cc][t] + accL[3][cc][t];
    Hs[(size_t)cc * NPIX + (size_t)row * 512 + t] = v;
  }
}

// ---- fused flow + reintegrate: 16x16 output tile ----
// stage 22x22 halo of (h0,h1,h2,xsum,x0,x1,x2) in planar LDS once;
// sobel + mu + reintegration all read LDS.
__global__ void flow_reint(const float* __restrict__ x, const float* __restrict__ Hs,
                           float* __restrict__ out) {
  __shared__ float tS[7][496];     // 22*22=484 used, planar (conflict-free)
  __shared__ float muT[400 * 6];
  int ox = (blockIdx.x >> 5) << 4;
  int oy = (blockIdx.x & 31) << 4;
  // pass 0: stage 22x22 tile (wrapped coords; all reads valid)
  for (int i = threadIdx.x; i < 484; i += 256) {
    int li = i / 22, lj = i % 22;
    int qx = (ox - 3 + li) & 511, qy = (oy - 3 + lj) & 511;
    int q = (qx << 9) | qy;
    float h0 = Hs[q], h1 = Hs[NPIX + q], h2 = Hs[2 * NPIX + q];
    float x0 = x[(size_t)q * 3 + 0], x1 = x[(size_t)q * 3 + 1], x2 = x[(size_t)q * 3 + 2];
    tS[0][i] = h0; tS[1][i] = h1; tS[2][i] = h2;
    tS[3][i] = x0 + x1 + x2;
    tS[4][i] = x0; tS[5][i] = x1; tS[6][i] = x2;
  }
  __syncthreads();
  // pass 1: sobel + flow + mu over the 20x20 halo, from LDS
  for (int i = threadIdx.x; i < 400; i += 256) {
    int hi = i / 20, hj = i % 20;
    int qx = (ox - 2 + hi) & 511, qy = (oy - 2 + hj) & 511;
    float syH0 = 0.f, syH1 = 0.f, syH2 = 0.f;
    float sxH0 = 0.f, sxH1 = 0.f, sxH2 = 0.f;
    float syX = 0.f, sxX = 0.f;
#pragma unroll
    for (int di = -1; di <= 1; ++di) {
#pragma unroll
      for (int dj = -1; dj <= 1; ++dj) {
        if (di == 0 && dj == 0) continue;
        int xi = qx + di, yj = qy + dj;
        if ((unsigned)xi >= 512u || (unsigned)yj >= 512u) continue;  // zero pad
        // valid neighbor in wrapped space == adjacent staged tile cell
        int l = (hi + 1 + di) * 22 + (hj + 1 + dj);
        float wy = (float)di * ((dj == 0) ? 2.f : 1.f);
        float wx = (float)dj * ((di == 0) ? 2.f : 1.f);
        float h0 = tS[0][l], h1 = tS[1][l], h2 = tS[2][l];
        syH0 += wy * h0; syH1 += wy * h1; syH2 += wy * h2;
        sxH0 += wx * h0; sxH1 += wx * h1; sxH2 += wx * h2;
        float xs = tS[3][l];
        syX += wy * xs; sxX += wx * xs;
      }
    }
    int lc = (hi + 1) * 22 + (hj + 1);
    float cxq = (float)qx + 0.5f, cyq = (float)qy + 0.5f;
    float syH[3] = {syH0, syH1, syH2};
    float sxH[3] = {sxH0, sxH1, sxH2};
    int b6 = i * 6;
#pragma unroll
    for (int c = 0; c < 3; ++c) {
      float xc = tS[4 + c][lc];
      float tt = xc * 0.5f;
      float alpha = fminf(tt * tt, 1.0f);
      float F0 = syH[c] * (1.f - alpha) - syX * alpha;
      float F1 = sxH[c] * (1.f - alpha) - sxX * alpha;
      float m0 = cxq + fminf(fmaxf(0.2f * F0, -1.05f), 1.05f);
      float m1 = cyq + fminf(fmaxf(0.2f * F1, -1.05f), 1.05f);
      muT[b6 + c]     = fminf(fmaxf(m0, 0.95f), 511.05f);
      muT[b6 + 3 + c] = fminf(fmaxf(m1, 0.95f), 511.05f);
    }
  }
  __syncthreads();
  // pass 2: 5x5 reintegration gather
  int o = threadIdx.x;
  int lx = o >> 4, ly = o & 15;
  int px_ = ox + lx, py_ = oy + ly;
  float cx = (float)px_ + 0.5f, cy = (float)py_ + 0.5f;
  float a0 = 0.f, a1 = 0.f, a2 = 0.f;
#pragma unroll
  for (int dx = -2; dx <= 2; ++dx) {
    int hi = lx + 2 - dx;
#pragma unroll
    for (int dy = -2; dy <= 2; ++dy) {
      int hj = ly + 2 - dy;
      int b6 = (hi * 20 + hj) * 6;
      int lb = (hi + 1) * 22 + (hj + 1);
      float wv;
      wv = fminf(fmaxf(1.45f - fabsf(cx - muT[b6 + 0]), 0.f), 1.f) *
           fminf(fmaxf(1.45f - fabsf(cy - muT[b6 + 3]), 0.f), 1.f);
      a0 += tS[4][lb] * wv;
      wv = fminf(fmaxf(1.45f - fabsf(cx - muT[b6 + 1]), 0.f), 1.f) *
           fminf(fmaxf(1.45f - fabsf(cy - muT[b6 + 4]), 0.f), 1.f);
      a1 += tS[5][lb] * wv;
      wv = fminf(fmaxf(1.45f - fabsf(cx - muT[b6 + 2]), 0.f), 1.f) *
           fminf(fmaxf(1.45f - fabsf(cy - muT[b6 + 5]), 0.f), 1.f);
      a2 += tS[6][lb] * wv;
    }
  }
  const float inv_area = 0.27700831f;  // 1/(4*0.95^2)
  size_t p = (size_t)((px_ << 9) | py_);
  out[p * 3 + 0] = a0 * inv_area;
  out[p * 3 + 1] = a1 * inv_area;
  out[p * 3 + 2] = a2 * inv_area;
}

extern "C" void kernel_launch(void* const* d_in, const int* in_sizes, int n_in,
                              void* d_out, int out_size, void* d_ws, size_t ws_size,
                              hipStream_t stream) {
  const float* x    = (const float*)d_in[0];
  const float* Ks   = (const float*)d_in[1];
  const float* m    = (const float*)d_in[2];
  const float* s    = (const float*)d_in[3];
  const float* h    = (const float*)d_in[4];
  const float* w_c1 = (const float*)d_in[5];
  const int*   c0   = (const int*)d_in[6];
  float* out = (float*)d_out;

  char* ws = (char*)d_ws;
  size_t off = 0;
  float* sums    = (float*)(ws + off); off += 1024;
  float* partial = (float*)(ws + off); off += 512 * 16 * 4;
  float2* AxH  = (float2*)(ws + off); off += (size_t)3 * 512 * HW * 8;    // 3.2 MB
  float2* AkH  = (float2*)(ws + off); off += (size_t)16 * 512 * HW * 8;   // 17.3 MB (plane 15 dummy)
  float2* FxT  = (float2*)(ws + off); off += (size_t)3 * HW * 512 * 8;    // 3.2 MB (transposed Fx)
  float*  Hs   = (float*)(ws + off);  off += (size_t)3 * NPIX * 4;        // 3 MB

  rows_all<<<608, 512, 0, stream>>>(Ks, x, partial, AkH, AxH);
  xcols<<<dim3(33, 3), 512, 0, stream>>>(AxH, FxT);
  fused_cols<<<dim3(34, NKER), 512, 0, stream>>>(AkH, FxT, c0, partial, sums);
  irows_growth_combine<<<512, 512, 0, stream>>>(AkH, sums, m, s, h, w_c1, Hs);
  flow_reint<<<1024, 256, 0, stream>>>(x, Hs, out);
}

// Round 5
// 126.303 us; speedup vs baseline: 1.1040x; 1.0091x over previous
//
#include <hip/hip_runtime.h>
#include <math.h>

#define NPIX 262144   // 512*512
#define NKER 15
#define PI_F 3.14159265358979323846f
#define HW 264        // half-plane row stride (float2): 257 used, padded to 8
#define HWR 264       // real-plane row stride (float): 257 used, padded to 8
#define CS 578        // wave scratch stride (float2): >= SK(511)=574
#define SK(n) ((n) + ((n) >> 3))   // skewed LDS index: <=4-way conflicts

__device__ __forceinline__ float2 cadd(float2 a, float2 b) { return make_float2(a.x + b.x, a.y + b.y); }
__device__ __forceinline__ float2 csub(float2 a, float2 b) { return make_float2(a.x - b.x, a.y - b.y); }
__device__ __forceinline__ float2 cmul(float2 a, float2 b) {
  return make_float2(a.x * b.x - a.y * b.y, a.x * b.y + a.y * b.x);
}
__device__ __forceinline__ float2 cmulc(float2 a, float2 b) {   // a * conj(b)
  return make_float2(a.x * b.x + a.y * b.y, a.y * b.x - a.x * b.y);
}

// Per-thread twiddle power tables: pA[q-1] = w1^q, pB[q-1] = wh^q (q=1..7).
__device__ __forceinline__ void build_tw(int lane, float2* pA, float2* pB) {
  float s, c;
  sincosf(-2.0f * PI_F * (float)lane / 512.0f, &s, &c);
  float2 w1 = make_float2(c, s);
  int h = lane & ~7;
  float2 wh = make_float2(__shfl(c, h, 64), __shfl(s, h, 64));
  pA[0] = w1;
  pA[1] = cmul(w1, w1);
  pA[2] = cmul(pA[1], w1);
  pA[3] = cmul(pA[1], pA[1]);
  pA[4] = cmul(pA[3], w1);
  pA[5] = cmul(pA[3], pA[1]);
  pA[6] = cmul(pA[3], pA[2]);
  pB[0] = wh;
  pB[1] = cmul(wh, wh);
  pB[2] = cmul(pB[1], wh);
  pB[3] = cmul(pB[1], pB[1]);
  pB[4] = cmul(pB[3], wh);
  pB[5] = cmul(pB[3], pB[1]);
  pB[6] = cmul(pB[3], pB[2]);
}

template <bool INV>
__device__ __forceinline__ void dft8(float2 a[8]) {
  const float R = 0.70710678118654752f;
  float2 t0 = cadd(a[0], a[4]), u0 = csub(a[0], a[4]);
  float2 t1 = cadd(a[1], a[5]), u1 = csub(a[1], a[5]);
  float2 t2 = cadd(a[2], a[6]), u2 = csub(a[2], a[6]);
  float2 t3 = cadd(a[3], a[7]), u3 = csub(a[3], a[7]);
  u1 = INV ? make_float2(R * (u1.x - u1.y), R * (u1.x + u1.y))
           : make_float2(R * (u1.x + u1.y), R * (u1.y - u1.x));
  u2 = INV ? make_float2(-u2.y, u2.x) : make_float2(u2.y, -u2.x);
  u3 = INV ? make_float2(-R * (u3.x + u3.y), R * (u3.x - u3.y))
           : make_float2(R * (u3.y - u3.x), -R * (u3.x + u3.y));
  float2 e0 = cadd(t0, t2), f0 = csub(t0, t2);
  float2 e1 = cadd(t1, t3), f1 = csub(t1, t3);
  f1 = INV ? make_float2(-f1.y, f1.x) : make_float2(f1.y, -f1.x);
  float2 g0 = cadd(u0, u2), h0 = csub(u0, u2);
  float2 g1 = cadd(u1, u3), h1 = csub(u1, u3);
  h1 = INV ? make_float2(-h1.y, h1.x) : make_float2(h1.y, -h1.x);
  a[0] = cadd(e0, e1); a[4] = csub(e0, e1);
  a[2] = cadd(f0, f1); a[6] = csub(f0, f1);
  a[1] = cadd(g0, g1); a[5] = csub(g0, g1);
  a[3] = cadd(h0, h1); a[7] = csub(h0, h1);
}

// 512-pt Stockham radix-8, one wave, 8 pts/thread, a[q] = point (lane+64q).
template <bool INV>
__device__ __forceinline__ void fft512_r8(float2 a[8], float2* buf, int lane,
                                          const float2* pA, const float2* pB) {
  dft8<INV>(a);
#pragma unroll
  for (int q = 1; q < 8; ++q) a[q] = INV ? cmulc(a[q], pA[q - 1]) : cmul(a[q], pA[q - 1]);
#pragma unroll
  for (int q = 0; q < 8; ++q) buf[9 * lane + q] = a[q];
#pragma unroll
  for (int q = 0; q < 8; ++q) a[q] = buf[SK(lane + 64 * q)];
  dft8<INV>(a);
#pragma unroll
  for (int q = 1; q < 8; ++q) a[q] = INV ? cmulc(a[q], pB[q - 1]) : cmul(a[q], pB[q - 1]);
  int h = lane & ~7;
  int b2 = 9 * h + (lane - h);
#pragma unroll
  for (int q = 0; q < 8; ++q) buf[b2 + 9 * q] = a[q];
#pragma unroll
  for (int q = 0; q < 8; ++q) a[q] = buf[SK(lane + 64 * q)];
  dft8<INV>(a);
}

// After packed FFT Z of (seqA + i seqB), seqA/seqB REAL: half-plane split.
__device__ __forceinline__ void split_store_halfplane(float2 a[8], float2* buf, int lane,
                                                      float2* d0, float2* d1) {
#pragma unroll
  for (int q = 0; q < 8; ++q) buf[SK(lane + 64 * q)] = a[q];
#pragma unroll
  for (int q = 0; q < 4; ++q) {
    int v = lane + 64 * q;
    int mir = (512 - v) & 511;
    float2 P = a[q];
    float2 Qc = buf[SK(mir)];
    float2 Q = make_float2(Qc.x, -Qc.y);
    d0[v] = make_float2(0.5f * (P.x + Q.x), 0.5f * (P.y + Q.y));
    d1[v] = make_float2(0.5f * (P.y - Q.y), -0.5f * (P.x - Q.x));
  }
  if (lane == 0) {
    float2 P = a[4];
    d0[256] = make_float2(P.x, 0.f);
    d1[256] = make_float2(P.y, 0.f);
  }
}

// ---- rows_all (512 threads, 8 waves) ----
// blocks 0..511: kernel row FFTs. Rows of the fftshifted ring kernels are
//   EXACTLY even (bitwise: value depends on |signed index| only), so the
//   packed pair spectrum separates trivially: Fk1 = Re Z, Fk2 = Im Z, both
//   REAL -> store real planes AkR (half the bytes, no mirror round-trip).
//   Exact-zero rows skip the FFT (bit-exact).
// blocks 512..607: R2C row FFTs of x (general real rows -> conj split).
__global__ __launch_bounds__(512, 4) void rows_all(
    const float* __restrict__ Ks, const float* __restrict__ x,
    float* __restrict__ partial, float* __restrict__ AkR,
    float2* __restrict__ AxH) {
  __shared__ float krow[512 * NKER];   // 30720 B
  __shared__ float2 scr[8][CS];        // 36992 B
  __shared__ float psum[480];          // 1920 B
  int t = threadIdx.x, wave = t >> 6, lane = t & 63;
  float2 pA[7], pB[7];
  build_tw(lane, pA, pB);
  if (blockIdx.x < 512) {
    int b = blockIdx.x;              // output row
    int rs = (b + 256) & 511;        // fftshift row source
    const float2* src = (const float2*)Ks + (size_t)rs * 3840;
    float2* kr2 = (float2*)krow;
    for (int i = t; i < 3840; i += 512) kr2[i] = src[i];
    __syncthreads();
    // row sums: 15 k x 32 y-groups of 16
    if (t < 480) {
      int k = t >> 5, yg = t & 31;
      float s = 0.f;
      int base = yg * 16;
#pragma unroll
      for (int y = 0; y < 16; ++y) s += krow[(base + y) * NKER + k];
      psum[t] = s;
    }
    // one packed k-pair FFT per wave
    {
      int k1 = 2 * wave, k2 = k1 + 1;     // k2==15 -> dummy plane
      float2 a[8];
      bool nz = false;
#pragma unroll
      for (int q = 0; q < 8; ++q) {
        int ys = (lane + 64 * q + 256) & 511;   // fftshift col
        float re = krow[ys * NKER + k1];
        float im = (k2 < NKER) ? krow[ys * NKER + k2] : 0.f;
        a[q] = make_float2(re, im);
        nz |= (re != 0.f) || (im != 0.f);
      }
      float* d0 = AkR + ((size_t)k1 * 512 + b) * HWR;
      float* d1 = AkR + ((size_t)k2 * 512 + b) * HWR;   // plane 15 = scratch
      if (__any((int)nz)) {
        fft512_r8<false>(a, &scr[wave][0], lane, pA, pB);
        // even rows -> both spectra real: Fk1 = Re, Fk2 = Im. cols 0..256.
#pragma unroll
        for (int q = 0; q < 4; ++q) {
          int v = lane + 64 * q;
          d0[v] = a[q].x; d1[v] = a[q].y;
        }
        if (lane == 0) { d0[256] = a[4].x; d1[256] = a[4].y; }
      } else {
#pragma unroll
        for (int q = 0; q < 4; ++q) {
          int v = lane + 64 * q;
          d0[v] = 0.f; d1[v] = 0.f;
        }
        if (lane == 0) { d0[256] = 0.f; d1[256] = 0.f; }
      }
    }
    __syncthreads();
    if (t < NKER) {
      float s = 0.f;
#pragma unroll
      for (int g = 0; g < 32; ++g) s += psum[(t << 5) + g];
      partial[b * 16 + t] = s;
    }
  } else {
    int job = (blockIdx.x - 512) * 8 + wave;   // 0..767
    int c = job >> 8;                // channel 0..2
    int rp = job & 255;              // row-pair 0..255
    int r0 = rp, r1 = rp + 256;
    float2 a[8];
#pragma unroll
    for (int q = 0; q < 8; ++q) {
      int y = lane + 64 * q;
      a[q] = make_float2(x[((size_t)r0 * 512 + y) * 3 + c],
                         x[((size_t)r1 * 512 + y) * 3 + c]);
    }
    fft512_r8<false>(a, &scr[wave][0], lane, pA, pB);
    float2* d0 = AxH + ((size_t)c * 512 + r0) * HW;
    float2* d1 = AxH + ((size_t)c * 512 + r1) * HW;
    split_store_halfplane(a, &scr[wave][0], lane, d0, d1);
  }
}

// ---- xkcols: column FFTs for BOTH x (complex, per channel) and kernels
//      (real-even, packed k-pairs: Fk1 = Re, Fk2 = Im). Outputs transposed
//      (FxT complex / FkT real) for coalesced consumption in fused_cols.
//      grid (34, 11): by<3 x-channel jobs, by 3..10 k-pair jobs;
//      bx==33,by==0 = ksum reduction. ----
__global__ __launch_bounds__(512, 4) void xkcols(
    const float2* __restrict__ AxH, const float* __restrict__ AkR,
    float2* __restrict__ FxT, float* __restrict__ FkT,
    const float* __restrict__ partial, float* __restrict__ sums) {
  __shared__ float2 buf[8 * CS];   // 36992 B
  __shared__ float red[512];
  int t = threadIdx.x;
  if (blockIdx.x == 33) {
    if (blockIdx.y != 0) return;
    int k = t & 15, g = t >> 4;        // 32 groups x 16 slots
    float acc = 0.f;
    for (int b = g; b < 512; b += 32) acc += partial[b * 16 + k];
    red[t] = acc;
    __syncthreads();
    if (t < 16) {
      float s = 0.f;
#pragma unroll
      for (int g2 = 0; g2 < 32; ++g2) s += red[g2 * 16 + t];
      sums[t] = s;
    }
    return;
  }
  int c = t >> 6, lane = t & 63;
  int col0 = blockIdx.x << 3;
  float2 pA[7], pB[7];
  build_tw(lane, pA, pB);
  if (blockIdx.y < 3) {
    // x-channel column FFT (complex input)
    int ch = blockIdx.y;
    const float2* bx = AxH + (size_t)ch * 512 * HW;
#pragma unroll
    for (int u = 0; u < 8; ++u) {
      int idx = (u << 9) + t;
      int row = idx >> 3, cc = idx & 7;
      buf[cc * CS + SK(row)] = bx[(size_t)row * HW + col0 + cc];
    }
    __syncthreads();
    float2 a[8];
#pragma unroll
    for (int q = 0; q < 8; ++q) a[q] = buf[c * CS + SK(lane + 64 * q)];
    fft512_r8<false>(a, &buf[c * CS], lane, pA, pB);
    float2* dst = FxT + ((size_t)ch * HW + col0 + c) * 512;
#pragma unroll
    for (int q = 0; q < 8; ++q) dst[lane + 64 * q] = a[q];
  } else {
    // kernel pair column FFT: real even cols -> Fk1 = Re, Fk2 = Im
    int pr = blockIdx.y - 3;           // 0..7
    int k1 = 2 * pr, k2 = k1 + 1;      // k2==15 -> dummy plane
    const float* s1 = AkR + (size_t)k1 * 512 * HWR;
    const float* s2 = AkR + (size_t)k2 * 512 * HWR;
#pragma unroll
    for (int u = 0; u < 8; ++u) {
      int idx = (u << 9) + t;
      int row = idx >> 3, cc = idx & 7;
      buf[cc * CS + row] = make_float2(s1[(size_t)row * HWR + col0 + cc],
                                       s2[(size_t)row * HWR + col0 + cc]);
    }
    __syncthreads();
    float2 a[8];
#pragma unroll
    for (int q = 0; q < 8; ++q) a[q] = buf[c * CS + lane + 64 * q];
    fft512_r8<false>(a, &buf[c * CS], lane, pA, pB);
    float* e1 = FkT + ((size_t)k1 * HWR + col0 + c) * 512;
    float* e2 = FkT + ((size_t)k2 * HWR + col0 + c) * 512;
#pragma unroll
    for (int q = 0; q < 8; ++q) {
      int v = lane + 64 * q;
      e1[v] = a[q].x;
      e2[v] = a[q].y;
    }
  }
}

// ---- fused column product pass (512 threads, grid (33,15)):
//      read real Fk (coalesced) + complex Fx (coalesced) -> P = Fk*Fx ->
//      ONE inverse col FFT -> transposed write of product rows to AkH.
//      No input staging, no forward FFT, single barrier. ----
__global__ __launch_bounds__(512, 4) void fused_cols(
    float2* __restrict__ AkH, const float* __restrict__ FkT,
    const float2* __restrict__ FxT, const int* __restrict__ c0) {
  __shared__ float2 buf[8 * CS];   // 36992 B
  int t = threadIdx.x;
  int col0 = blockIdx.x << 3, k = blockIdx.y;
  int c = t >> 6, lane = t & 63;
  float2 pA[7], pB[7];
  build_tw(lane, pA, pB);
  const float* fk = FkT + ((size_t)k * HWR + col0 + c) * 512;
  const float2* fx = FxT + ((size_t)c0[k] * HW + col0 + c) * 512;
  float2 a[8];
#pragma unroll
  for (int q = 0; q < 8; ++q) {
    int v = lane + 64 * q;
    float s = fk[v];
    float2 xv = fx[v];
    a[q] = make_float2(s * xv.x, s * xv.y);
  }
  fft512_r8<true>(a, &buf[c * CS], lane, pA, pB);
#pragma unroll
  for (int q = 0; q < 8; ++q) buf[c * CS + SK(lane + 64 * q)] = a[q];
  __syncthreads();
  float2* bk = AkH + (size_t)k * 512 * HW;
#pragma unroll
  for (int u = 0; u < 8; ++u) {
    int idx = (u << 9) + t;
    int row = idx >> 3, cc = idx & 7;
    bk[(size_t)row * HW + col0 + cc] = buf[cc * CS + SK(row)];
  }
}

// ---- C2R inverse row FFT + deferred norm + growth + combine -> Hs ----
__global__ __launch_bounds__(512, 4) void irows_growth_combine(
    const float2* __restrict__ AkH, const float* __restrict__ sums,
    const float* __restrict__ m, const float* __restrict__ s,
    const float* __restrict__ h, const float* __restrict__ w,
    float* __restrict__ Hs) {
  __shared__ float2 scr[8][CS];        // 36992 B
  __shared__ float accL[4][3][512];    // 24576 B
  __shared__ float mk[16], isk[16], hk[16], wk[16][3], sck[16];
  int t = threadIdx.x, wave = t >> 6, lane = t & 63;
  int row = blockIdx.x;
  if (t < NKER) {
    mk[t] = m[t]; isk[t] = 1.0f / s[t]; hk[t] = h[t];
    sck[t] = 1.0f / (sums[t] * 262144.0f);
    wk[t][0] = w[t * 3 + 0]; wk[t][1] = w[t * 3 + 1]; wk[t][2] = w[t * 3 + 2];
  }
  __syncthreads();
  float2 pA[7], pB[7];
  build_tw(lane, pA, pB);
  float acc[3][8];
#pragma unroll
  for (int cc = 0; cc < 3; ++cc)
#pragma unroll
    for (int q = 0; q < 8; ++q) acc[cc][q] = 0.f;
  {
    int slot = wave;
    int k1 = 2 * slot, k2 = 2 * slot + 1;
    bool dual = (k2 < NKER);
    const float2* p1 = AkH + ((size_t)k1 * 512 + row) * HW;
    const float2* p2 = AkH + ((size_t)(dual ? k2 : k1) * 512 + row) * HW;
    float2 a[8];
#pragma unroll
    for (int q = 0; q < 8; ++q) {
      int v = lane + 64 * q;
      if (v <= 256) {
        float2 A1 = p1[v];
        float2 A2 = dual ? p2[v] : make_float2(0.f, 0.f);
        a[q] = make_float2(A1.x - A2.y, A1.y + A2.x);          // A1 + i*A2
      } else {
        int mi = 512 - v;
        float2 A1 = p1[mi];
        float2 A2 = dual ? p2[mi] : make_float2(0.f, 0.f);
        a[q] = make_float2(A1.x + A2.y, -A1.y + A2.x);         // conj(A1) + i*conj(A2)
      }
    }
    fft512_r8<true>(a, &scr[wave][0], lane, pA, pB);
    float m1 = mk[k1], i1 = isk[k1], h1 = hk[k1], s1 = sck[k1];
    float w10 = wk[k1][0], w11 = wk[k1][1], w12 = wk[k1][2];
#pragma unroll
    for (int q = 0; q < 8; ++q) {
      float tt = (a[q].x * s1 - m1) * i1;
      float g = (expf(-0.5f * tt * tt) * 2.0f - 1.0f) * h1;
      acc[0][q] += g * w10; acc[1][q] += g * w11; acc[2][q] += g * w12;
    }
    if (dual) {
      float m2 = mk[k2], i2 = isk[k2], h2 = hk[k2], s2 = sck[k2];
      float w20 = wk[k2][0], w21 = wk[k2][1], w22 = wk[k2][2];
#pragma unroll
      for (int q = 0; q < 8; ++q) {
        float tt = (a[q].y * s2 - m2) * i2;
        float g = (expf(-0.5f * tt * tt) * 2.0f - 1.0f) * h2;
        acc[0][q] += g * w20; acc[1][q] += g * w21; acc[2][q] += g * w22;
      }
    }
  }
  if (wave < 4) {
#pragma unroll
    for (int cc = 0; cc < 3; ++cc)
#pragma unroll
      for (int q = 0; q < 8; ++q) accL[wave][cc][lane + 64 * q] = acc[cc][q];
  }
  __syncthreads();
  if (wave >= 4) {
#pragma unroll
    for (int cc = 0; cc < 3; ++cc)
#pragma unroll
      for (int q = 0; q < 8; ++q) accL[wave - 4][cc][lane + 64 * q] += acc[cc][q];
  }
  __syncthreads();
#pragma unroll
  for (int cc = 0; cc < 3; ++cc) {
    float v = accL[0][cc][t] + accL[1][cc][t] + accL[2][cc][t] + accL[3][cc][t];
    Hs[(size_t)cc * NPIX + (size_t)row * 512 + t] = v;
  }
}

// ---- fused flow + reintegrate: 16x16 output tile ----
__global__ void flow_reint(const float* __restrict__ x, const float* __restrict__ Hs,
                           float* __restrict__ out) {
  __shared__ float tS[7][496];     // 22*22=484 used, planar (conflict-free)
  __shared__ float muT[400 * 6];
  int ox = (blockIdx.x >> 5) << 4;
  int oy = (blockIdx.x & 31) << 4;
  for (int i = threadIdx.x; i < 484; i += 256) {
    int li = i / 22, lj = i % 22;
    int qx = (ox - 3 + li) & 511, qy = (oy - 3 + lj) & 511;
    int q = (qx << 9) | qy;
    float h0 = Hs[q], h1 = Hs[NPIX + q], h2 = Hs[2 * NPIX + q];
    float x0 = x[(size_t)q * 3 + 0], x1 = x[(size_t)q * 3 + 1], x2 = x[(size_t)q * 3 + 2];
    tS[0][i] = h0; tS[1][i] = h1; tS[2][i] = h2;
    tS[3][i] = x0 + x1 + x2;
    tS[4][i] = x0; tS[5][i] = x1; tS[6][i] = x2;
  }
  __syncthreads();
  for (int i = threadIdx.x; i < 400; i += 256) {
    int hi = i / 20, hj = i % 20;
    int qx = (ox - 2 + hi) & 511, qy = (oy - 2 + hj) & 511;
    float syH0 = 0.f, syH1 = 0.f, syH2 = 0.f;
    float sxH0 = 0.f, sxH1 = 0.f, sxH2 = 0.f;
    float syX = 0.f, sxX = 0.f;
#pragma unroll
    for (int di = -1; di <= 1; ++di) {
#pragma unroll
      for (int dj = -1; dj <= 1; ++dj) {
        if (di == 0 && dj == 0) continue;
        int xi = qx + di, yj = qy + dj;
        if ((unsigned)xi >= 512u || (unsigned)yj >= 512u) continue;  // zero pad
        int l = (hi + 1 + di) * 22 + (hj + 1 + dj);
        float wy = (float)di * ((dj == 0) ? 2.f : 1.f);
        float wx = (float)dj * ((di == 0) ? 2.f : 1.f);
        float h0 = tS[0][l], h1 = tS[1][l], h2 = tS[2][l];
        syH0 += wy * h0; syH1 += wy * h1; syH2 += wy * h2;
        sxH0 += wx * h0; sxH1 += wx * h1; sxH2 += wx * h2;
        float xs = tS[3][l];
        syX += wy * xs; sxX += wx * xs;
      }
    }
    int lc = (hi + 1) * 22 + (hj + 1);
    float cxq = (float)qx + 0.5f, cyq = (float)qy + 0.5f;
    float syH[3] = {syH0, syH1, syH2};
    float sxH[3] = {sxH0, sxH1, sxH2};
    int b6 = i * 6;
#pragma unroll
    for (int c = 0; c < 3; ++c) {
      float xc = tS[4 + c][lc];
      float tt = xc * 0.5f;
      float alpha = fminf(tt * tt, 1.0f);
      float F0 = syH[c] * (1.f - alpha) - syX * alpha;
      float F1 = sxH[c] * (1.f - alpha) - sxX * alpha;
      float m0 = cxq + fminf(fmaxf(0.2f * F0, -1.05f), 1.05f);
      float m1 = cyq + fminf(fmaxf(0.2f * F1, -1.05f), 1.05f);
      muT[b6 + c]     = fminf(fmaxf(m0, 0.95f), 511.05f);
      muT[b6 + 3 + c] = fminf(fmaxf(m1, 0.95f), 511.05f);
    }
  }
  __syncthreads();
  int o = threadIdx.x;
  int lx = o >> 4, ly = o & 15;
  int px_ = ox + lx, py_ = oy + ly;
  float cx = (float)px_ + 0.5f, cy = (float)py_ + 0.5f;
  float a0 = 0.f, a1 = 0.f, a2 = 0.f;
#pragma unroll
  for (int dx = -2; dx <= 2; ++dx) {
    int hi = lx + 2 - dx;
#pragma unroll
    for (int dy = -2; dy <= 2; ++dy) {
      int hj = ly + 2 - dy;
      int b6 = (hi * 20 + hj) * 6;
      int lb = (hi + 1) * 22 + (hj + 1);
      float wv;
      wv = fminf(fmaxf(1.45f - fabsf(cx - muT[b6 + 0]), 0.f), 1.f) *
           fminf(fmaxf(1.45f - fabsf(cy - muT[b6 + 3]), 0.f), 1.f);
      a0 += tS[4][lb] * wv;
      wv = fminf(fmaxf(1.45f - fabsf(cx - muT[b6 + 1]), 0.f), 1.f) *
           fminf(fmaxf(1.45f - fabsf(cy - muT[b6 + 4]), 0.f), 1.f);
      a1 += tS[5][lb] * wv;
      wv = fminf(fmaxf(1.45f - fabsf(cx - muT[b6 + 2]), 0.f), 1.f) *
           fminf(fmaxf(1.45f - fabsf(cy - muT[b6 + 5]), 0.f), 1.f);
      a2 += tS[6][lb] * wv;
    }
  }
  const float inv_area = 0.27700831f;  // 1/(4*0.95^2)
  size_t p = (size_t)((px_ << 9) | py_);
  out[p * 3 + 0] = a0 * inv_area;
  out[p * 3 + 1] = a1 * inv_area;
  out[p * 3 + 2] = a2 * inv_area;
}

extern "C" void kernel_launch(void* const* d_in, const int* in_sizes, int n_in,
                              void* d_out, int out_size, void* d_ws, size_t ws_size,
                              hipStream_t stream) {
  const float* x    = (const float*)d_in[0];
  const float* Ks   = (const float*)d_in[1];
  const float* m    = (const float*)d_in[2];
  const float* s    = (const float*)d_in[3];
  const float* h    = (const float*)d_in[4];
  const float* w_c1 = (const float*)d_in[5];
  const int*   c0   = (const int*)d_in[6];
  float* out = (float*)d_out;

  char* ws = (char*)d_ws;
  size_t off = 0;
  float* sums    = (float*)(ws + off); off += 1024;
  float* partial = (float*)(ws + off); off += 512 * 16 * 4;
  float2* AxH  = (float2*)(ws + off); off += (size_t)3 * 512 * HW * 8;    // 3.2 MB
  float2* AkH  = (float2*)(ws + off); off += (size_t)16 * 512 * HW * 8;   // 17.3 MB (products)
  float2* FxT  = (float2*)(ws + off); off += (size_t)3 * HW * 512 * 8;    // 3.2 MB
  float*  AkR  = (float*)(ws + off);  off += (size_t)16 * 512 * HWR * 4;  // 8.65 MB (real row spectra)
  float*  FkT  = (float*)(ws + off);  off += (size_t)16 * HWR * 512 * 4;  // 8.65 MB (real 2D spectra, transposed)
  float*  Hs   = (float*)(ws + off);  off += (size_t)3 * NPIX * 4;        // 3 MB

  rows_all<<<608, 512, 0, stream>>>(Ks, x, partial, AkR, AxH);
  xkcols<<<dim3(34, 11), 512, 0, stream>>>(AxH, AkR, FxT, FkT, partial, sums);
  fused_cols<<<dim3(33, NKER), 512, 0, stream>>>(AkH, FkT, FxT, c0);
  irows_growth_combine<<<512, 512, 0, stream>>>(AkH, sums, m, s, h, w_c1, Hs);
  flow_reint<<<1024, 256, 0, stream>>>(x, Hs, out);
}